// Round 1
// baseline (190.495 us; speedup 1.0000x reference)
//
#include <hip/hip_runtime.h>
#include <math.h>

// Problem constants (reference file)
#define B_ 2
#define H_ 1080
#define W_ 1920
#define K_ 2048
#define P_ 256
#define PITCH_ (W_ + 1)          // 1921 doubles per SAT row
#define SROWS_ (H_ + 1)          // 1081 SAT rows
#define SATSZ_ ((size_t)B_ * SROWS_ * PITCH_)   // doubles

// ---------------------------------------------------------------------------
// SAT build: sat[b][y+1][x+1] = sum_{i<=y, j<=x} image[b][i][j]  (double)
// ---------------------------------------------------------------------------

__global__ void zero_row0_kernel(double* __restrict__ sat) {
  int t = blockIdx.x * blockDim.x + threadIdx.x;
  if (t < B_ * PITCH_) {
    int b = t / PITCH_;
    int x = t - b * PITCH_;
    sat[(size_t)b * SROWS_ * PITCH_ + x] = 0.0;
  }
}

// One 64-lane wave per image row: chunked inclusive shuffle-scan.
__global__ void row_scan_kernel(const float* __restrict__ img,
                                double* __restrict__ sat) {
  int gid = blockIdx.x * blockDim.x + threadIdx.x;
  int wave = gid >> 6;
  int lane = gid & 63;
  if (wave >= B_ * H_) return;
  int b = wave / H_;
  int y = wave - b * H_;
  const float* row = img + ((size_t)b * H_ + y) * W_;
  double* srow = sat + ((size_t)b * SROWS_ + (size_t)(y + 1)) * PITCH_;
  if (lane == 0) srow[0] = 0.0;  // SAT column 0
  double carry = 0.0;
  for (int x0 = 0; x0 < W_; x0 += 64) {   // W_ = 30*64, no tail
    double v = (double)row[x0 + lane];
    #pragma unroll
    for (int off = 1; off < 64; off <<= 1) {
      double n = __shfl_up(v, off, 64);
      if (lane >= off) v += n;
    }
    v += carry;
    srow[x0 + lane + 1] = v;
    carry = __shfl(v, 63, 64);
  }
}

// One thread per (b, x): serial down-column accumulation, unroll 8 so the
// 8 loads of an iteration pipeline ahead of the dependent stores.
__global__ void col_scan_kernel(double* __restrict__ sat) {
  int t = blockIdx.x * blockDim.x + threadIdx.x;
  if (t >= B_ * PITCH_) return;
  int b = t / PITCH_;
  int x = t - b * PITCH_;
  double* base = sat + (size_t)b * SROWS_ * PITCH_ + x;
  double c = 0.0;
  for (int y = 1; y <= H_; y += 8) {      // H_ = 135*8, no tail
    double a0 = base[(size_t)(y + 0) * PITCH_];
    double a1 = base[(size_t)(y + 1) * PITCH_];
    double a2 = base[(size_t)(y + 2) * PITCH_];
    double a3 = base[(size_t)(y + 3) * PITCH_];
    double a4 = base[(size_t)(y + 4) * PITCH_];
    double a5 = base[(size_t)(y + 5) * PITCH_];
    double a6 = base[(size_t)(y + 6) * PITCH_];
    double a7 = base[(size_t)(y + 7) * PITCH_];
    c += a0; base[(size_t)(y + 0) * PITCH_] = c;
    c += a1; base[(size_t)(y + 1) * PITCH_] = c;
    c += a2; base[(size_t)(y + 2) * PITCH_] = c;
    c += a3; base[(size_t)(y + 3) * PITCH_] = c;
    c += a4; base[(size_t)(y + 4) * PITCH_] = c;
    c += a5; base[(size_t)(y + 5) * PITCH_] = c;
    c += a6; base[(size_t)(y + 6) * PITCH_] = c;
    c += a7; base[(size_t)(y + 7) * PITCH_] = c;
  }
}

// ---------------------------------------------------------------------------
// Descriptor kernel: one block per (b,k), one thread per pair p.
// ---------------------------------------------------------------------------

__device__ __forceinline__ float box_sample(const double* __restrict__ satb,
                                            float py, float px, int r, float w) {
  // reference: jy = clip(round(py), 0, H-1); round = half-to-even (rintf)
  int jy = (int)fminf(fmaxf(rintf(py), 0.0f), (float)(H_ - 1));
  int jx = (int)fminf(fmaxf(rintf(px), 0.0f), (float)(W_ - 1));
  int y0 = max(jy - r, 0);
  int y1 = min(jy + r, H_ - 1);
  int x0 = max(jx - r, 0);
  int x1 = min(jx + r, W_ - 1);
  const double* rt = satb + (size_t)y0 * PITCH_;
  const double* rb = satb + (size_t)(y1 + 1) * PITCH_;
  double s = rb[x1 + 1] - rb[x0] - rt[x1 + 1] + rt[x0];
  return __fmul_rn((float)s, w);   // zero padding: denom stays (2r+1)^2
}

__global__ __launch_bounds__(256) void bad_desc_kernel(
    const float* __restrict__ kp, const float* __restrict__ orient,
    const float* __restrict__ oy1, const float* __restrict__ ox1,
    const float* __restrict__ oy2, const float* __restrict__ ox2,
    const float* __restrict__ thr, const int* __restrict__ radii,
    const double* __restrict__ sat, float* __restrict__ out) {
  int bk = blockIdx.x;              // b*K + k
  int b = bk >> 11;                 // K_ = 2048
  float kpy = kp[(size_t)bk * 2 + 0];
  float kpx = kp[(size_t)bk * 2 + 1];
  float validf = (kpy >= 0.0f) ? 1.0f : 0.0f;
  float y = fminf(fmaxf(kpy, 0.0f), (float)(H_ - 1));
  float x = fminf(fmaxf(kpx, 0.0f), (float)(W_ - 1));
  int iy = (int)rintf(y);
  int ix = (int)rintf(x);
  float theta = orient[((size_t)b * H_ + iy) * W_ + ix];
  // double-precision sin/cos rounded to fp32 = correctly-rounded fp32
  double td = (double)theta;
  float st = (float)sin(td);
  float ct = (float)cos(td);

  int p = threadIdx.x;
  float a_y1 = oy1[p], a_x1 = ox1[p], a_y2 = oy2[p], a_x2 = ox2[p];
  // strict fp32, no FMA contraction, same op order as reference
  float rdy1 = __fadd_rn(__fmul_rn(a_x1, st), __fmul_rn(a_y1, ct));
  float rdx1 = __fsub_rn(__fmul_rn(a_x1, ct), __fmul_rn(a_y1, st));
  float rdy2 = __fadd_rn(__fmul_rn(a_x2, st), __fmul_rn(a_y2, ct));
  float rdx2 = __fsub_rn(__fmul_rn(a_x2, ct), __fmul_rn(a_y2, st));
  float p1y = __fadd_rn(y, rdy1);
  float p1x = __fadd_rn(x, rdx1);
  float p2y = __fadd_rn(y, rdy2);
  float p2x = __fadd_rn(x, rdx2);

  int r = radii[p];
  float tt = 2.0f * (float)r + 1.0f;
  float w = __fdiv_rn(1.0f, __fmul_rn(tt, tt));   // fp32(1/(2r+1)^2)

  const double* satb = sat + (size_t)b * SROWS_ * PITCH_;
  float v1 = box_sample(satb, p1y, p1x, r, w);
  float v2 = box_sample(satb, p2y, p2x, r, w);
  float d = __fsub_rn(__fsub_rn(v1, v2), thr[p]);

  // block L2-norm over P=256: wave shuffle reduce + 4-wave LDS combine
  float sq = __fmul_rn(d, d);
  #pragma unroll
  for (int off = 32; off >= 1; off >>= 1) sq += __shfl_xor(sq, off, 64);
  __shared__ float wsum[4];
  int lane = p & 63, wv = p >> 6;
  if (lane == 0) wsum[wv] = sq;
  __syncthreads();
  float total = wsum[0] + wsum[1] + wsum[2] + wsum[3];
  float norm = sqrtf(total);
  float q = __fdiv_rn(d, fmaxf(norm, 1e-12f));
  out[(size_t)bk * P_ + p] = __fmul_rn(q, validf);
}

// ---------------------------------------------------------------------------

extern "C" void kernel_launch(void* const* d_in, const int* in_sizes, int n_in,
                              void* d_out, int out_size, void* d_ws, size_t ws_size,
                              hipStream_t stream) {
  const float* image    = (const float*)d_in[0];
  const float* kp       = (const float*)d_in[1];
  const float* orient   = (const float*)d_in[2];
  const float* oy1      = (const float*)d_in[3];
  const float* ox1      = (const float*)d_in[4];
  const float* oy2      = (const float*)d_in[5];
  const float* ox2      = (const float*)d_in[6];
  const float* thr      = (const float*)d_in[7];
  const int*   radii    = (const int*)d_in[8];
  float* out = (float*)d_out;
  double* sat = (double*)d_ws;   // needs B_*1081*1921*8 = ~33.2 MB

  {
    int n = B_ * PITCH_;
    zero_row0_kernel<<<(n + 255) / 256, 256, 0, stream>>>(sat);
  }
  {
    int waves = B_ * H_;                    // 2160 rows, 4 waves/block
    int blocks = (waves + 3) / 4;
    row_scan_kernel<<<blocks, 256, 0, stream>>>(image, sat);
  }
  {
    int n = B_ * PITCH_;
    col_scan_kernel<<<(n + 255) / 256, 256, 0, stream>>>(sat);
  }
  {
    bad_desc_kernel<<<B_ * K_, 256, 0, stream>>>(
        kp, orient, oy1, ox1, oy2, ox2, thr, radii, sat, out);
  }
}

// Round 2
// 122.328 us; speedup vs baseline: 1.5572x; 1.5572x over previous
//
#include <hip/hip_runtime.h>
#include <math.h>

// Problem constants (reference file)
#define B_ 2
#define H_ 1080
#define W_ 1920
#define K_ 2048
#define P_ 256
#define SROWS_ (H_ + 1)          // 1081 SAT rows
#define RP_ 1924                 // padded floats per SAT row (mult of 4)
// SAT row layout: R = sat + (b*SROWS_+y)*RP_ ; R[0]=pad, R[1+x]=SAT(y,x) for
// x in [0,1920] (x=0 is the zero column), R[1922..1923]=pad.
// The +1 front pad makes the float2 stores at R[x0+2*lane+2] 8B-aligned.
#define NSEG_ 27
#define SEGH_ 40                 // 27*40 = 1080 rows per column

// ---------------------------------------------------------------------------
// Row scan: one 64-lane wave per image row, float2 chunks, shuffle scan.
// SAT(y+1, x) = prefix over image row y. Also zeroes SAT row 0 (y==0 wave).
// ---------------------------------------------------------------------------
__global__ void row_scan_kernel(const float* __restrict__ img,
                                float* __restrict__ sat) {
  int gid = blockIdx.x * blockDim.x + threadIdx.x;
  int wave = gid >> 6;
  int lane = gid & 63;
  if (wave >= B_ * H_) return;
  int b = wave / H_;
  int y = wave - b * H_;
  const float* row = img + ((size_t)b * H_ + y) * W_;
  float* R = sat + ((size_t)b * SROWS_ + (size_t)(y + 1)) * RP_;
  if (lane == 0) R[1] = 0.0f;              // zero column
  if (y == 0) {                            // fused: zero SAT row 0
    float* R0 = sat + (size_t)b * SROWS_ * RP_;
    if (lane == 0) R0[1] = 0.0f;
    for (int x0 = 0; x0 < W_; x0 += 128)
      *(float2*)(R0 + x0 + 2 * lane + 2) = make_float2(0.0f, 0.0f);
  }
  float carry = 0.0f;
  for (int x0 = 0; x0 < W_; x0 += 128) {   // 15 chunks, no tail
    float2 a = *(const float2*)(row + x0 + 2 * lane);
    float s = a.x + a.y;
    float S = s;
    #pragma unroll
    for (int off = 1; off < 64; off <<= 1) {
      float n = __shfl_up(S, off, 64);
      if (lane >= off) S += n;
    }
    float excl = carry + (S - s);          // lane-exclusive prefix + carry
    float2 o;
    o.x = excl + a.x;
    o.y = o.x + a.y;
    *(float2*)(R + x0 + 2 * lane + 2) = o;
    carry += __shfl(S, 63, 64);
  }
}

// ---------------------------------------------------------------------------
// Column scan, hierarchical: phase 1 = per-(column, 40-row segment) sums.
// Processes all RP_ columns (pads harmless, never read downstream).
// ---------------------------------------------------------------------------
__global__ void col_partial_kernel(float* __restrict__ sat) {
  int t = blockIdx.x * blockDim.x + threadIdx.x;
  if (t >= B_ * NSEG_ * RP_) return;
  int c = t % RP_;
  int rest = t / RP_;
  int seg = rest % NSEG_;
  int b = rest / NSEG_;
  const float* base = sat + ((size_t)b * SROWS_ + 1 + (size_t)seg * SEGH_) * RP_ + c;
  float s = 0.0f;
  #pragma unroll 8
  for (int j = 0; j < SEGH_; ++j) s += base[(size_t)j * RP_];
  float* segsum = sat + (size_t)B_ * SROWS_ * RP_;
  segsum[(size_t)(b * NSEG_ + seg) * RP_ + c] = s;
}

// Phase 2: offset = sum of preceding segment sums, then 40-row RMW sweep.
__global__ void col_apply_kernel(float* __restrict__ sat) {
  int t = blockIdx.x * blockDim.x + threadIdx.x;
  if (t >= B_ * NSEG_ * RP_) return;
  int c = t % RP_;
  int rest = t / RP_;
  int seg = rest % NSEG_;
  int b = rest / NSEG_;
  const float* segsum = sat + (size_t)B_ * SROWS_ * RP_ + (size_t)b * NSEG_ * RP_ + c;
  float off = 0.0f;
  for (int s = 0; s < seg; ++s) off += segsum[(size_t)s * RP_];
  float* base = sat + ((size_t)b * SROWS_ + 1 + (size_t)seg * SEGH_) * RP_ + c;
  float acc = off;
  for (int j = 0; j < SEGH_; j += 8) {     // preload 8 for MLP, serial adds
    float a0 = base[(size_t)(j + 0) * RP_];
    float a1 = base[(size_t)(j + 1) * RP_];
    float a2 = base[(size_t)(j + 2) * RP_];
    float a3 = base[(size_t)(j + 3) * RP_];
    float a4 = base[(size_t)(j + 4) * RP_];
    float a5 = base[(size_t)(j + 5) * RP_];
    float a6 = base[(size_t)(j + 6) * RP_];
    float a7 = base[(size_t)(j + 7) * RP_];
    acc += a0; base[(size_t)(j + 0) * RP_] = acc;
    acc += a1; base[(size_t)(j + 1) * RP_] = acc;
    acc += a2; base[(size_t)(j + 2) * RP_] = acc;
    acc += a3; base[(size_t)(j + 3) * RP_] = acc;
    acc += a4; base[(size_t)(j + 4) * RP_] = acc;
    acc += a5; base[(size_t)(j + 5) * RP_] = acc;
    acc += a6; base[(size_t)(j + 6) * RP_] = acc;
    acc += a7; base[(size_t)(j + 7) * RP_] = acc;
  }
}

// ---------------------------------------------------------------------------
// Descriptor kernel: one block per (b,k), one thread per pair p.
// ---------------------------------------------------------------------------
__device__ __forceinline__ float box_sample(const float* __restrict__ satb,
                                            float py, float px, int r, float w) {
  // reference: jy = clip(round(py), 0, H-1); round = half-to-even (rintf)
  int jy = (int)fminf(fmaxf(rintf(py), 0.0f), (float)(H_ - 1));
  int jx = (int)fminf(fmaxf(rintf(px), 0.0f), (float)(W_ - 1));
  int y0 = max(jy - r, 0);
  int y1 = min(jy + r, H_ - 1);
  int x0 = max(jx - r, 0);
  int x1 = min(jx + r, W_ - 1);
  const float* rt = satb + (size_t)y0 * RP_ + 1;
  const float* rb = satb + (size_t)(y1 + 1) * RP_ + 1;
  float s = ((rb[x1 + 1] - rb[x0]) - rt[x1 + 1]) + rt[x0];
  return __fmul_rn(s, w);   // zero padding: denom stays (2r+1)^2
}

__global__ __launch_bounds__(256) void bad_desc_kernel(
    const float* __restrict__ kp, const float* __restrict__ orient,
    const float* __restrict__ oy1, const float* __restrict__ ox1,
    const float* __restrict__ oy2, const float* __restrict__ ox2,
    const float* __restrict__ thr, const int* __restrict__ radii,
    const float* __restrict__ sat, float* __restrict__ out) {
  int bk = blockIdx.x;              // b*K + k
  int b = bk >> 11;                 // K_ = 2048
  float kpy = kp[(size_t)bk * 2 + 0];
  float kpx = kp[(size_t)bk * 2 + 1];
  float validf = (kpy >= 0.0f) ? 1.0f : 0.0f;
  float y = fminf(fmaxf(kpy, 0.0f), (float)(H_ - 1));
  float x = fminf(fmaxf(kpx, 0.0f), (float)(W_ - 1));
  int iy = (int)rintf(y);
  int ix = (int)rintf(x);
  float theta = orient[((size_t)b * H_ + iy) * W_ + ix];
  // double-precision sin/cos rounded to fp32 = correctly-rounded fp32
  double td = (double)theta;
  float st = (float)sin(td);
  float ct = (float)cos(td);

  int p = threadIdx.x;
  float a_y1 = oy1[p], a_x1 = ox1[p], a_y2 = oy2[p], a_x2 = ox2[p];
  // strict fp32, no FMA contraction, same op order as reference
  float rdy1 = __fadd_rn(__fmul_rn(a_x1, st), __fmul_rn(a_y1, ct));
  float rdx1 = __fsub_rn(__fmul_rn(a_x1, ct), __fmul_rn(a_y1, st));
  float rdy2 = __fadd_rn(__fmul_rn(a_x2, st), __fmul_rn(a_y2, ct));
  float rdx2 = __fsub_rn(__fmul_rn(a_x2, ct), __fmul_rn(a_y2, st));
  float p1y = __fadd_rn(y, rdy1);
  float p1x = __fadd_rn(x, rdx1);
  float p2y = __fadd_rn(y, rdy2);
  float p2x = __fadd_rn(x, rdx2);

  int r = radii[p];
  float tt = 2.0f * (float)r + 1.0f;
  float w = __fdiv_rn(1.0f, __fmul_rn(tt, tt));   // fp32(1/(2r+1)^2)

  const float* satb = sat + (size_t)b * SROWS_ * RP_;
  float v1 = box_sample(satb, p1y, p1x, r, w);
  float v2 = box_sample(satb, p2y, p2x, r, w);
  float d = __fsub_rn(__fsub_rn(v1, v2), thr[p]);

  // block L2-norm over P=256: wave shuffle reduce + 4-wave LDS combine
  float sq = __fmul_rn(d, d);
  #pragma unroll
  for (int off = 32; off >= 1; off >>= 1) sq += __shfl_xor(sq, off, 64);
  __shared__ float wsum[4];
  int lane = p & 63, wv = p >> 6;
  if (lane == 0) wsum[wv] = sq;
  __syncthreads();
  float total = wsum[0] + wsum[1] + wsum[2] + wsum[3];
  float norm = sqrtf(total);
  float q = __fdiv_rn(d, fmaxf(norm, 1e-12f));
  out[(size_t)bk * P_ + p] = __fmul_rn(q, validf);
}

// ---------------------------------------------------------------------------

extern "C" void kernel_launch(void* const* d_in, const int* in_sizes, int n_in,
                              void* d_out, int out_size, void* d_ws, size_t ws_size,
                              hipStream_t stream) {
  const float* image    = (const float*)d_in[0];
  const float* kp       = (const float*)d_in[1];
  const float* orient   = (const float*)d_in[2];
  const float* oy1      = (const float*)d_in[3];
  const float* ox1      = (const float*)d_in[4];
  const float* oy2      = (const float*)d_in[5];
  const float* ox2      = (const float*)d_in[6];
  const float* thr      = (const float*)d_in[7];
  const int*   radii    = (const int*)d_in[8];
  float* out = (float*)d_out;
  float* sat = (float*)d_ws;   // SAT (16.6 MB) + segsums (0.42 MB)

  {
    int waves = B_ * H_;                    // 2160 rows, 4 waves/block
    int blocks = (waves + 3) / 4;
    row_scan_kernel<<<blocks, 256, 0, stream>>>(image, sat);
  }
  {
    int n = B_ * NSEG_ * RP_;
    col_partial_kernel<<<(n + 255) / 256, 256, 0, stream>>>(sat);
    col_apply_kernel<<<(n + 255) / 256, 256, 0, stream>>>(sat);
  }
  {
    bad_desc_kernel<<<B_ * K_, 256, 0, stream>>>(
        kp, orient, oy1, ox1, oy2, ox2, thr, radii, sat, out);
  }
}